// Round 1
// baseline (973.889 us; speedup 1.0000x reference)
//
#include <hip/hip_runtime.h>

// Problem constants (from reference)
#define NN   1000000
#define D    128
#define DV4  32          // D / 4 floats per float4
#define BATCH 1024
#define LW   40          // walk length
#define WIN  5
#define NP   370         // pairs per walk
#define NEG  5
#define NPB  (NP * NEG)  // 1850 negatives per walk
#define NPAIR_TOT (BATCH * NP)   // 378880

// Pair index table, generated to match reference _make_pair_idx loop order exactly.
struct Tab { short src[NP]; short dst[NP]; };
constexpr Tab mk_tab() {
  Tab t{};
  int n = 0;
  for (int i = 0; i < LW; i++) {
    int lo = i - WIN; if (lo < 0) lo = 0;
    for (int j = lo; j < i; j++) { t.src[n] = (short)j; t.dst[n] = (short)i; n++; }
    int hi = i + 1 + WIN; if (hi > LW) hi = LW;
    for (int j = i + 1; j < hi; j++) { t.src[n] = (short)j; t.dst[n] = (short)i; n++; }
  }
  return t;
}
__constant__ Tab g_tab = mk_tab();

// Kernel 1: gather context rows for all B*L flat positions into contiguous ws.
// grid: BATCH*LW*DV4 / 256 threads, one float4 per thread.
__global__ __launch_bounds__(256) void gather_ctx(
    const float4* __restrict__ ctx, const int* __restrict__ walk,
    float4* __restrict__ out) {
  int g = blockIdx.x * blockDim.x + threadIdx.x;   // [0, 40960*32)
  int p = g >> 5;      // flat position
  int c = g & 31;      // float4 column
  int idx = walk[p];   // broadcast within 32 threads
  out[p * DV4 + c] = ctx[(long long)idx * DV4 + c];
}

// Kernel 2: one block per walk. Stage node+ctx rows in LDS, compute pos+neg
// losses. 32-lane groups: one dot product per group-iteration.
__global__ __launch_bounds__(256) void sgns_kernel(
    const float4* __restrict__ node_embed,
    const float4* __restrict__ ctx_embed,   // fallback path only
    const int* __restrict__ walk,
    const int* __restrict__ neg_idx,
    const float4* __restrict__ ctxg,        // gathered ctx in ws (may be null)
    float* __restrict__ out) {
  __shared__ float4 sNode[LW * DV4];   // 20480 B
  __shared__ float4 sCtx[LW * DV4];    // 20480 B  (total 40960 = 40 KiB)

  const int b = blockIdx.x;
  const int tid = threadIdx.x;

  // Stage: 1280 float4 per array, 256 threads -> 5 iterations each.
  for (int e = tid; e < LW * DV4; e += 256) {
    int row = e >> 5;
    int c = e & 31;
    int idx = walk[b * LW + row];                       // broadcast, cached
    sNode[e] = node_embed[(long long)idx * DV4 + c];
    if (ctxg) sCtx[e] = ctxg[(size_t)(b * LW + row) * DV4 + c]; // contiguous
    else      sCtx[e] = ctx_embed[(long long)idx * DV4 + c];
  }
  __syncthreads();

  const int grp = tid >> 5;   // 8 groups of 32 lanes
  const int l = tid & 31;
  float acc = 0.f;

  // Positive pairs: dot(node[src], ctx[dst]) from LDS.
  for (int k = grp; k < NP; k += 8) {
    int s = g_tab.src[k];
    int d = g_tab.dst[k];
    float4 a = sNode[s * DV4 + l];
    float4 c = sCtx[d * DV4 + l];
    float p = a.x * c.x + a.y * c.y + a.z * c.z + a.w * c.w;
    p += __shfl_xor(p, 1);  p += __shfl_xor(p, 2);  p += __shfl_xor(p, 4);
    p += __shfl_xor(p, 8);  p += __shfl_xor(p, 16);
    if (l == 0) {
      float sc = fminf(fmaxf(p, -6.f), 6.f);
      acc += __logf(1.f + __expf(-sc));   // -log_sigmoid(sc)
    }
  }

  // Negative pairs: dot(node[dst-of-pair], ctx_gathered[neg_idx]).
  const int nb = b * NPB;
  for (int t = grp; t < NPB; t += 8) {
    int j = neg_idx[nb + t];            // flat position in [0, B*L)
    int d = g_tab.dst[t / NEG];         // uniform within group
    float4 a = sNode[d * DV4 + l];
    float4 c;
    if (ctxg) c = ctxg[(size_t)j * DV4 + l];               // 512B coalesced row
    else      c = ctx_embed[(long long)walk[j] * DV4 + l]; // double indirection
    float p = a.x * c.x + a.y * c.y + a.z * c.z + a.w * c.w;
    p += __shfl_xor(p, 1);  p += __shfl_xor(p, 2);  p += __shfl_xor(p, 4);
    p += __shfl_xor(p, 8);  p += __shfl_xor(p, 16);
    if (l == 0) {
      float sc = fminf(fmaxf(p, -6.f), 6.f);
      acc += __logf(1.f + __expf(sc));    // -log_sigmoid(-sc)
    }
  }

  // Block reduction: full-wave butterfly, then 4 wave sums via reused LDS.
  acc += __shfl_xor(acc, 1);  acc += __shfl_xor(acc, 2);  acc += __shfl_xor(acc, 4);
  acc += __shfl_xor(acc, 8);  acc += __shfl_xor(acc, 16); acc += __shfl_xor(acc, 32);
  __syncthreads();                       // done reading sNode; reuse as scratch
  float* sRed = (float*)sNode;
  if ((tid & 63) == 0) sRed[tid >> 6] = acc;
  __syncthreads();
  if (tid == 0) {
    float s = sRed[0] + sRed[1] + sRed[2] + sRed[3];
    atomicAdd(out, s * (1.f / (float)NPAIR_TOT));
  }
}

extern "C" void kernel_launch(void* const* d_in, const int* in_sizes, int n_in,
                              void* d_out, int out_size, void* d_ws, size_t ws_size,
                              hipStream_t stream) {
  const float* node_embed = (const float*)d_in[0];
  const float* ctx_embed  = (const float*)d_in[1];
  const int*   walk       = (const int*)d_in[2];
  const int*   neg        = (const int*)d_in[3];
  float* out = (float*)d_out;

  hipMemsetAsync(d_out, 0, sizeof(float), stream);

  const size_t need = (size_t)BATCH * LW * D * sizeof(float);  // ~21 MB
  float4* ctxg = nullptr;
  if (ws_size >= need) {
    ctxg = (float4*)d_ws;
    int total = BATCH * LW * DV4;      // 1,310,720 threads
    gather_ctx<<<total / 256, 256, 0, stream>>>(
        (const float4*)ctx_embed, walk, ctxg);
  }

  sgns_kernel<<<BATCH, 256, 0, stream>>>(
      (const float4*)node_embed, (const float4*)ctx_embed, walk, neg, ctxg, out);
}

// Round 2
// 882.000 us; speedup vs baseline: 1.1042x; 1.1042x over previous
//
#include <hip/hip_runtime.h>

// Problem constants (from reference)
#define NN   1000000
#define D    128
#define DV4  32          // D / 4 floats per float4
#define BATCH 1024
#define LW   40          // walk length
#define WIN  5
#define NP   370         // pairs per walk
#define NEG  5
#define NPB  (NP * NEG)  // 1850 negatives per walk
#define NPAIR_TOT (BATCH * NP)   // 378880

// Pair index table, generated to match reference _make_pair_idx loop order exactly.
struct Tab { short src[NP]; short dst[NP]; };
constexpr Tab mk_tab() {
  Tab t{};
  int n = 0;
  for (int i = 0; i < LW; i++) {
    int lo = i - WIN; if (lo < 0) lo = 0;
    for (int j = lo; j < i; j++) { t.src[n] = (short)j; t.dst[n] = (short)i; n++; }
    int hi = i + 1 + WIN; if (hi > LW) hi = LW;
    for (int j = i + 1; j < hi; j++) { t.src[n] = (short)j; t.dst[n] = (short)i; n++; }
  }
  return t;
}
__constant__ Tab g_tab = mk_tab();

// Kernel 1: gather context rows for all B*L flat positions into contiguous ws.
__global__ __launch_bounds__(256) void gather_ctx(
    const float4* __restrict__ ctx, const int* __restrict__ walk,
    float4* __restrict__ out) {
  int g = blockIdx.x * blockDim.x + threadIdx.x;   // [0, 40960*32)
  int p = g >> 5;      // flat position
  int c = g & 31;      // float4 column
  int idx = walk[p];   // broadcast within 32 threads
  out[p * DV4 + c] = ctx[(long long)idx * DV4 + c];
}

__device__ __forceinline__ float dot4(float4 a, float4 c) {
  return a.x * c.x + a.y * c.y + a.z * c.z + a.w * c.w;
}
__device__ __forceinline__ float red32(float p) {
  p += __shfl_xor(p, 1);  p += __shfl_xor(p, 2);  p += __shfl_xor(p, 4);
  p += __shfl_xor(p, 8);  p += __shfl_xor(p, 16);
  return p;
}

// Kernel 2: one block per walk, 512 threads = 16 groups of 32 lanes.
// LDS: node rows (20 KiB) + neg indices (7.4 KB). ~28 KiB -> 4 blocks/CU
// (wave-capped), full 32-wave occupancy at grid=1024.
__global__ __launch_bounds__(512) void sgns_kernel(
    const float4* __restrict__ node_embed,
    const float4* __restrict__ ctx_embed,   // fallback path only
    const int* __restrict__ walk,
    const int* __restrict__ neg_idx,
    const float4* __restrict__ ctxg,        // gathered ctx in ws (may be null)
    float* __restrict__ out) {
  __shared__ float4 sNode[LW * DV4];   // 20480 B
  __shared__ int sIdx[NPB];            // 7400 B

  const int b = blockIdx.x;
  const int tid = threadIdx.x;

  // Stage node rows: 1280 float4, 512 threads -> 2.5 iterations.
  for (int e = tid; e < LW * DV4; e += 512) {
    int row = e >> 5;
    int c = e & 31;
    int idx = walk[b * LW + row];
    sNode[e] = node_embed[(long long)idx * DV4 + c];
  }
  // Stage negative indices (coalesced int reads).
  for (int t = tid; t < NPB; t += 512) sIdx[t] = neg_idx[b * NPB + t];
  __syncthreads();

  const int grp = tid >> 5;   // 16 groups
  const int l = tid & 31;
  float acc = 0.f;

  // Positive pairs: node from LDS, ctx from the walk's contiguous gathered
  // slice (L1/L2-hot, 20 KB) or fallback via walk indirection.
  const float4* cwalk = ctxg ? (ctxg + (size_t)b * LW * DV4) : nullptr;
  for (int k = grp; k < NP; k += 16) {
    int s = g_tab.src[k];
    int d = g_tab.dst[k];
    float4 a = sNode[s * DV4 + l];
    const float4* crow = cwalk ? (cwalk + d * DV4)
                               : (ctx_embed + (long long)walk[b * LW + d] * DV4);
    float p = red32(dot4(a, crow[l]));
    if (l == 0) {
      float sc = fminf(fmaxf(p, -6.f), 6.f);
      acc += __logf(1.f + __expf(-sc));   // -log_sigmoid(sc)
    }
  }

  // Negative pairs, unrolled x4: 4 independent row loads in flight.
  int t = grp;
  for (; t + 48 < NPB; t += 64) {
    int j0 = sIdx[t], j1 = sIdx[t + 16], j2 = sIdx[t + 32], j3 = sIdx[t + 48];
    const float4* r0 = ctxg ? (ctxg + (size_t)j0 * DV4) : (ctx_embed + (long long)walk[j0] * DV4);
    const float4* r1 = ctxg ? (ctxg + (size_t)j1 * DV4) : (ctx_embed + (long long)walk[j1] * DV4);
    const float4* r2 = ctxg ? (ctxg + (size_t)j2 * DV4) : (ctx_embed + (long long)walk[j2] * DV4);
    const float4* r3 = ctxg ? (ctxg + (size_t)j3 * DV4) : (ctx_embed + (long long)walk[j3] * DV4);
    float4 c0 = r0[l], c1 = r1[l], c2 = r2[l], c3 = r3[l];
    float4 a0 = sNode[g_tab.dst[t / NEG] * DV4 + l];
    float4 a1 = sNode[g_tab.dst[(t + 16) / NEG] * DV4 + l];
    float4 a2 = sNode[g_tab.dst[(t + 32) / NEG] * DV4 + l];
    float4 a3 = sNode[g_tab.dst[(t + 48) / NEG] * DV4 + l];
    float p0 = red32(dot4(a0, c0));
    float p1 = red32(dot4(a1, c1));
    float p2 = red32(dot4(a2, c2));
    float p3 = red32(dot4(a3, c3));
    // Batch the 4 softplus evals on lanes 0..3 (all lanes hold all sums).
    float sel = (l == 0) ? p0 : (l == 1) ? p1 : (l == 2) ? p2 : p3;
    if (l < 4) {
      float sc = fminf(fmaxf(sel, -6.f), 6.f);
      acc += __logf(1.f + __expf(sc));    // -log_sigmoid(-sc)
    }
  }
  for (; t < NPB; t += 16) {
    int j = sIdx[t];
    const float4* r = ctxg ? (ctxg + (size_t)j * DV4) : (ctx_embed + (long long)walk[j] * DV4);
    float4 a = sNode[g_tab.dst[t / NEG] * DV4 + l];
    float p = red32(dot4(a, r[l]));
    if (l == 0) {
      float sc = fminf(fmaxf(p, -6.f), 6.f);
      acc += __logf(1.f + __expf(sc));
    }
  }

  // Block reduction.
  acc += __shfl_xor(acc, 1);  acc += __shfl_xor(acc, 2);  acc += __shfl_xor(acc, 4);
  acc += __shfl_xor(acc, 8);  acc += __shfl_xor(acc, 16); acc += __shfl_xor(acc, 32);
  __syncthreads();                       // done reading sNode; reuse as scratch
  float* sRed = (float*)sNode;
  if ((tid & 63) == 0) sRed[tid >> 6] = acc;
  __syncthreads();
  if (tid == 0) {
    float s = 0.f;
    for (int w = 0; w < 8; w++) s += sRed[w];
    atomicAdd(out, s * (1.f / (float)NPAIR_TOT));
  }
}

extern "C" void kernel_launch(void* const* d_in, const int* in_sizes, int n_in,
                              void* d_out, int out_size, void* d_ws, size_t ws_size,
                              hipStream_t stream) {
  const float* node_embed = (const float*)d_in[0];
  const float* ctx_embed  = (const float*)d_in[1];
  const int*   walk       = (const int*)d_in[2];
  const int*   neg        = (const int*)d_in[3];
  float* out = (float*)d_out;

  hipMemsetAsync(d_out, 0, sizeof(float), stream);

  const size_t need = (size_t)BATCH * LW * D * sizeof(float);  // ~21 MB
  float4* ctxg = nullptr;
  if (ws_size >= need) {
    ctxg = (float4*)d_ws;
    int total = BATCH * LW * DV4;      // 1,310,720 threads
    gather_ctx<<<total / 256, 256, 0, stream>>>(
        (const float4*)ctx_embed, walk, ctxg);
  }

  sgns_kernel<<<BATCH, 512, 0, stream>>>(
      (const float4*)node_embed, (const float4*)ctx_embed, walk, neg, ctxg, out);
}